// Round 1
// 207.410 us; speedup vs baseline: 1.0356x; 1.0356x over previous
//
#include <hip/hip_runtime.h>

typedef __attribute__((ext_vector_type(8))) short short8;
typedef __attribute__((ext_vector_type(4))) float floatx4;

#define TOKENS 2048
#define IN_F   4096
#define OUT_F  4096
#define NITER  20

#define INV_2PI 0.15915494309189535f
#define TWO_PI  6.283185307179586f

// round-to-nearest-even f32 -> bf16 bits
__device__ __forceinline__ unsigned short f2bf(float f) {
    unsigned int u = __builtin_bit_cast(unsigned int, f);
    u += 0x7fffu + ((u >> 16) & 1u);
    return (unsigned short)(u >> 16);
}

// one fractal step in REVOLUTION units: v' = a*v + (b/2pi)*sin(2pi*v)
__device__ __forceinline__ void step4(float4& v, float a, float bc) {
    v.x = __builtin_fmaf(bc, __builtin_amdgcn_sinf(v.x), a * v.x);
    v.y = __builtin_fmaf(bc, __builtin_amdgcn_sinf(v.y), a * v.y);
    v.z = __builtin_fmaf(bc, __builtin_amdgcn_sinf(v.z), a * v.z);
    v.w = __builtin_fmaf(bc, __builtin_amdgcn_sinf(v.w), a * v.w);
}

#define WBLOCKS (OUT_F * IN_F / 8 / 256)   // 8192
#define XBLOCKS (TOKENS * IN_F / 8 / 256)  // 4096

// Fused: blocks [0,8192) transcribe seed->w_bf (20 iters); [8192,12288) cast x->x_bf.
__global__ __launch_bounds__(256) void transcribe_fused_kernel(
    const float4* __restrict__ seed, const float4* __restrict__ xin,
    const float* __restrict__ da, const float* __restrict__ db,
    short8* __restrict__ w_out, short8* __restrict__ x_out)
{
    const int b = blockIdx.x;
    short8 o;
    if (b < WBLOCKS) {
        int i = b * 256 + threadIdx.x;
        float4 u = seed[2 * i];
        float4 v = seed[2 * i + 1];
        u.x *= INV_2PI; u.y *= INV_2PI; u.z *= INV_2PI; u.w *= INV_2PI;
        v.x *= INV_2PI; v.y *= INV_2PI; v.z *= INV_2PI; v.w *= INV_2PI;
#pragma unroll
        for (int t = 0; t < NITER; t++) {
            float a = da[t], bc = db[t] * INV_2PI;
            step4(u, a, bc);
            step4(v, a, bc);
        }
        o[0] = (short)f2bf(u.x * TWO_PI); o[1] = (short)f2bf(u.y * TWO_PI);
        o[2] = (short)f2bf(u.z * TWO_PI); o[3] = (short)f2bf(u.w * TWO_PI);
        o[4] = (short)f2bf(v.x * TWO_PI); o[5] = (short)f2bf(v.y * TWO_PI);
        o[6] = (short)f2bf(v.z * TWO_PI); o[7] = (short)f2bf(v.w * TWO_PI);
        w_out[i] = o;
    } else {
        int i = (b - WBLOCKS) * 256 + threadIdx.x;
        float4 u = xin[2 * i];
        float4 v = xin[2 * i + 1];
        o[0] = (short)f2bf(u.x); o[1] = (short)f2bf(u.y);
        o[2] = (short)f2bf(u.z); o[3] = (short)f2bf(u.w);
        o[4] = (short)f2bf(v.x); o[5] = (short)f2bf(v.y);
        o[6] = (short)f2bf(v.z); o[7] = (short)f2bf(v.w);
        x_out[i] = o;
    }
}

// async 16B global -> LDS. Per-lane GLOBAL address; LDS dest = wave-uniform
// base + lane*16 (the +lane*8 ushort term below is uniform-folded by the
// compiler via readfirstlane — same idiom as the verified predecessor).
__device__ __forceinline__ void g2l16(const ushort* g, ushort* l) {
    __builtin_amdgcn_global_load_lds(
        (const __attribute__((address_space(1))) unsigned int*)g,
        (__attribute__((address_space(3))) unsigned int*)l, 16, 0, 0);
}

// ---------------------------------------------------------------------------
// GEMM: C[M,N] = A[M,K] * B[N,K]^T + bias[N];  A,B bf16 bits, C f32.
//
// BM=256 x BN=128 tile, BK=64, 512 threads = 8 waves in a 4(M) x 2(N) grid,
// per-wave 64x64 output (same 4x4 x 16x16x32 fragment pipeline as the
// verified 128x128 predecessor — fragment addressing/swizzle unchanged).
// Grid = 32x8 = 256 blocks = exactly 1 block/CU (vs 128 blocks for a 256^2
// tile at M=2048, which would idle half the CUs).
//
// Counted-vmcnt deep pipeline (T3+T4), 3-deep LDS ring (3 x 48 KiB = 144 KiB
// dynamic LDS):  per wave each K-tile issues 6 global_load_lds (A:4, B:2).
// Main loop waits vmcnt(12) = 2 tiles in flight — NEVER drains to 0 (the
// vmcnt(0)-at-barrier drain is the documented ~900 TF ceiling of the old
// 2-barrier structure).  Per tile:
//   vmcnt(12); s_barrier                       // tile t landed, t+1/t+2 in flight
//   ph A: ds_read slice0 (8xb128); setprio(1); 16 MFMA; setprio(0)
//   ph B: ds_read slice1; lgkmcnt(0); s_barrier   // all reads of this slot done
//         STAGE(tile t+3 -> this slot)            // 6 loads issued early
//         sched_barrier(0); setprio(1); 16 MFMA; setprio(0)
// Tail tiles wait vmcnt(12)/6/0.  Raw s_barrier (NOT __syncthreads — that
// would re-introduce the vmcnt(0) drain).  Barrier counts are wave-uniform.
//
// LDS swizzle (unchanged, measured 0 bank conflicts): 128B rows, physical
// 16B segment p of row r holds logical segment p ^ (r&7); global source is
// pre-swizzled, LDS dest stays linear (global_load_lds constraint).
// ---------------------------------------------------------------------------
#define BK     64
#define BM     256
#define BN     128
#define NT     (IN_F / BK)        // 64 K-tiles
#define ASLOT  (BM * BK)          // 16384 ushorts = 32 KiB
#define BSLOT  (BN * BK)          //  8192 ushorts = 16 KiB
#define LDS_BYTES (3 * (ASLOT + BSLOT) * 2)   // 147456 B = 144 KiB

__global__ __launch_bounds__(512, 2) void gemm_bt_kernel(
    const ushort* __restrict__ A,
    const ushort* __restrict__ B,
    const float* __restrict__ bias,
    float* __restrict__ C)
{
    extern __shared__ ushort lds[];
    ushort* As = lds;                  // [3][ASLOT]
    ushort* Bs = lds + 3 * ASLOT;      // [3][BSLOT]

    const int tid  = threadIdx.x;
    const int lane = tid & 63;
    const int wid  = tid >> 6;         // 0..7

    // XCD-aware swizzle: 256 blocks, 8 XCDs -> each XCD owns one bm stripe
    // (A-panel 2 MiB stays L2-resident per XCD; B streams via L3).
    const int bid = blockIdx.x;
    const int swz = (bid & 7) * 32 + (bid >> 3);
    const int bn  = swz & 31;          // 0..31
    const int bm  = swz >> 5;          // 0..7

    const int wm = (wid >> 1) << 6;    // 0,64,128,192  (M offset of wave)
    const int wn = (wid & 1) << 6;     // 0,64          (N offset of wave)
    const int fm = lane & 15;
    const int q  = lane >> 4;          // 0..3

    // staging: wave-instr covers 64 consecutive 16B chunks (8 rows x 8 segs);
    // lane = (row&7)*8 + pseg; global source segment = pseg ^ (row&7).
    const int gcol = (((lane & 7) ^ (lane >> 3)) << 3);

    const ushort* gA = A + (size_t)(bm * BM) * IN_F;
    const ushort* gB = B + (size_t)(bn * BN) * IN_F;

    floatx4 acc[4][4];
#pragma unroll
    for (int i = 0; i < 4; i++)
#pragma unroll
        for (int j = 0; j < 4; j++)
            acc[i][j] = (floatx4){0.f, 0.f, 0.f, 0.f};

    // A-slab: 2048 chunks -> 4 wave-instrs/wave; B-slab: 1024 -> 2/wave.
    // 6 VMEM instrs per wave per tile (the unit vmcnt counts in).
#define STAGE(k0v, sl)                                                        \
    {                                                                         \
        _Pragma("unroll")                                                     \
        for (int u = 0; u < 4; u++) {                                         \
            const int cb = ((u << 3) | wid) << 6;                             \
            const int r  = (cb >> 3) + (lane >> 3);                           \
            g2l16(gA + (size_t)r * IN_F + (k0v) + gcol,                       \
                  As + (sl) * ASLOT + cb * 8 + lane * 8);                     \
        }                                                                     \
        _Pragma("unroll")                                                     \
        for (int u = 0; u < 2; u++) {                                         \
            const int cb = ((u << 3) | wid) << 6;                             \
            const int r  = (cb >> 3) + (lane >> 3);                           \
            g2l16(gB + (size_t)r * IN_F + (k0v) + gcol,                       \
                  Bs + (sl) * BSLOT + cb * 8 + lane * 8);                     \
        }                                                                     \
    }

    // 8 x ds_read_b128 for k-slice s_ of slot sl (swizzled, conflict-free)
#define LOADFRAG(s_, sl)                                                      \
    const int sa = (((q + 4 * (s_)) & 7) ^ (fm & 7)) << 3;                    \
    _Pragma("unroll")                                                         \
    for (int i = 0; i < 4; i++) {                                             \
        af[i] = *(const short8*)(As + (sl) * ASLOT + (wm + i * 16 + fm) * BK + sa); \
        bf[i] = *(const short8*)(Bs + (sl) * BSLOT + (wn + i * 16 + fm) * BK + sa); \
    }

#define MFMA16()                                                              \
    __builtin_amdgcn_s_setprio(1);                                            \
    _Pragma("unroll")                                                         \
    for (int i = 0; i < 4; i++)                                               \
        _Pragma("unroll")                                                     \
        for (int j = 0; j < 4; j++)                                           \
            acc[i][j] = __builtin_amdgcn_mfma_f32_16x16x32_bf16(              \
                af[i], bf[j], acc[i][j], 0, 0, 0);                            \
    __builtin_amdgcn_s_setprio(0);

#define TILE_MAIN(vm, sl, k3)                                                 \
    {                                                                         \
        asm volatile("s_waitcnt vmcnt(" #vm ")" ::: "memory");                \
        __builtin_amdgcn_s_barrier();                                         \
        {                                                                     \
            short8 af[4], bf[4];                                              \
            LOADFRAG(0, sl);                                                  \
            MFMA16();                                                         \
        }                                                                     \
        {                                                                     \
            short8 af[4], bf[4];                                              \
            LOADFRAG(1, sl);                                                  \
            asm volatile("s_waitcnt lgkmcnt(0)" ::: "memory");                \
            __builtin_amdgcn_s_barrier();                                     \
            STAGE(k3, sl);                                                    \
            __builtin_amdgcn_sched_barrier(0);                                \
            MFMA16();                                                         \
        }                                                                     \
    }

#define TILE_TAIL(vm, sl)                                                     \
    {                                                                         \
        asm volatile("s_waitcnt vmcnt(" #vm ")" ::: "memory");                \
        __builtin_amdgcn_s_barrier();                                         \
        {                                                                     \
            short8 af[4], bf[4];                                              \
            LOADFRAG(0, sl);                                                  \
            MFMA16();                                                         \
        }                                                                     \
        {                                                                     \
            short8 af[4], bf[4];                                              \
            LOADFRAG(1, sl);                                                  \
            MFMA16();                                                         \
        }                                                                     \
    }

    // prologue: fill the 3-deep ring (18 loads/wave in flight)
    STAGE(0 * BK, 0);
    STAGE(1 * BK, 1);
    STAGE(2 * BK, 2);

    int st   = 0;
    int kpre = 3 * BK;
#pragma unroll 1
    for (int t = 0; t <= NT - 4; ++t) {        // t = 0..60, stages tiles 3..63
        TILE_MAIN(12, st, kpre);
        kpre += BK;
        st = (st == 2) ? 0 : st + 1;
    }
    // tail: tiles 61 (slot1), 62 (slot2), 63 (slot0); drain 12 -> 6 -> 0
    TILE_TAIL(12, 1);
    TILE_TAIL(6, 2);
    TILE_TAIL(0, 0);

#undef STAGE
#undef LOADFRAG
#undef MFMA16
#undef TILE_MAIN
#undef TILE_TAIL

    // epilogue: C/D layout col = lane&15, row = (lane>>4)*4 + reg  [m89-verified]
    const int cn = lane & 15;
    const int cm = (lane >> 4) << 2;
    float bv[4];
#pragma unroll
    for (int j = 0; j < 4; j++)
        bv[j] = bias[bn * BN + wn + j * 16 + cn];
#pragma unroll
    for (int i = 0; i < 4; i++) {
#pragma unroll
        for (int r = 0; r < 4; r++) {
            int m = bm * BM + wm + i * 16 + cm + r;
            float* crow = C + (size_t)m * OUT_F + bn * BN + wn + cn;
#pragma unroll
            for (int j = 0; j < 4; j++)
                crow[j * 16] = acc[i][j][r] + bv[j];
        }
    }
}

extern "C" void kernel_launch(void* const* d_in, const int* in_sizes, int n_in,
                              void* d_out, int out_size, void* d_ws, size_t ws_size,
                              hipStream_t stream) {
    const float* x    = (const float*)d_in[0];   // [2048, 4096]
    const float* seed = (const float*)d_in[1];   // [4096, 4096]
    const float* da   = (const float*)d_in[2];   // [20]
    const float* db   = (const float*)d_in[3];   // [20]
    const float* bias = (const float*)d_in[4];   // [4096]
    float* out        = (float*)d_out;           // [2048, 4096]

    ushort* w_bf = (ushort*)d_ws;                      // 32 MiB
    ushort* x_bf = w_bf + (size_t)OUT_F * IN_F;        // 16 MiB

    // allow 144 KiB dynamic LDS (one-time host-side attribute; not a stream op)
    static bool lds_attr_set = false;
    if (!lds_attr_set) {
        hipFuncSetAttribute(reinterpret_cast<const void*>(gemm_bt_kernel),
                            hipFuncAttributeMaxDynamicSharedMemorySize,
                            LDS_BYTES);
        lds_attr_set = true;
    }

    transcribe_fused_kernel<<<WBLOCKS + XBLOCKS, 256, 0, stream>>>(
        (const float4*)seed, (const float4*)x, da, db,
        (short8*)w_bf, (short8*)x_bf);

    gemm_bt_kernel<<<dim3(32 * 8), dim3(512), LDS_BYTES, stream>>>(
        x_bf, w_bf, bias, out);
}